// Round 4
// baseline (293.662 us; speedup 1.0000x reference)
//
#include <hip/hip_runtime.h>
#include <hip/hip_bf16.h>

typedef __bf16 bf16_t;
typedef __bf16 bf16x8 __attribute__((ext_vector_type(8)));
typedef float f32x4 __attribute__((ext_vector_type(4)));

__device__ __forceinline__ unsigned short f32_to_bf16_rn(float f) {
  unsigned u = __float_as_uint(f);
  u += 0x7fffu + ((u >> 16) & 1u);
  return (unsigned short)(u >> 16);
}

__device__ __forceinline__ float gelu_exact(float x) {
  return 0.5f * x * (1.0f + erff(x * 0.7071067811865475f));
}

// ---------------- cast x -> bf16 ----------------
__global__ void cast_x_kernel(const float* __restrict__ in,
                              unsigned short* __restrict__ out, int n4) {
  int i = blockIdx.x * blockDim.x + threadIdx.x;
  if (i >= n4) return;
  float4 v = ((const float4*)in)[i];
  ushort4 o;
  o.x = f32_to_bf16_rn(v.x);
  o.y = f32_to_bf16_rn(v.y);
  o.z = f32_to_bf16_rn(v.z);
  o.w = f32_to_bf16_rn(v.w);
  ((ushort4*)out)[i] = o;
}

// ---------------- build compacted index list (deterministic scan) ----------
__global__ void build_idx_kernel(const float* __restrict__ mask1,
                                 const float* __restrict__ mask2,
                                 int* __restrict__ idx, int* __restrict__ meta,
                                 int H, int D) {
  __shared__ int sums[1024];
  const int t = threadIdx.x;
  int flags[8];
  int tot = 0;
#pragma unroll
  for (int u = 0; u < 8; ++u) {
    int j = t * 8 + u;
    int f = (mask1[(long long)j * D] != 0.0f) && (mask2[j] != 0.0f);
    flags[u] = f;
    tot += f;
  }
  sums[t] = tot;
  __syncthreads();
  for (int off = 1; off < 1024; off <<= 1) {
    int v = (t >= off) ? sums[t - off] : 0;
    __syncthreads();
    sums[t] += v;
    __syncthreads();
  }
  int pos = sums[t] - tot;
#pragma unroll
  for (int u = 0; u < 8; ++u) {
    if (flags[u]) idx[pos++] = t * 8 + u;
  }
  if (t == 1023) {
    int count = sums[1023];
    meta[0] = count;
    meta[1] = (count + 127) & ~127;
  }
}

// ---------------- compact + cast w1 rows ----------------
__global__ void compact_w1_kernel(const float* __restrict__ w1,
                                  const int* __restrict__ idx,
                                  const int* __restrict__ meta,
                                  unsigned short* __restrict__ w1c, int D) {
  int q = blockIdx.x * blockDim.x + threadIdx.x;
  int k = q >> 9;
  int d4 = (q & 511) << 2;
  int count = meta[0];
  ushort4 o = {0, 0, 0, 0};
  if (k < count) {
    int j = idx[k];
    float4 v = *(const float4*)(w1 + (long long)j * D + d4);
    o.x = f32_to_bf16_rn(v.x);
    o.y = f32_to_bf16_rn(v.y);
    o.z = f32_to_bf16_rn(v.z);
    o.w = f32_to_bf16_rn(v.w);
  }
  *(ushort4*)(w1c + (long long)k * D + d4) = o;
}

// ---------------- compact + cast w2 cols (ld 4096) ----------------
__global__ void compact_w2_kernel(const float* __restrict__ w2,
                                  const int* __restrict__ idx,
                                  const int* __restrict__ meta,
                                  unsigned short* __restrict__ w2c, int H) {
  int q = blockIdx.x * blockDim.x + threadIdx.x;
  int n = q >> 10;
  int k4 = (q & 1023) << 2;
  int count = meta[0];
  ushort4 o = {0, 0, 0, 0};
  const float* src = w2 + (long long)n * H;
#pragma unroll
  for (int u = 0; u < 4; ++u) {
    int k = k4 + u;
    unsigned short v = 0;
    if (k < count) v = f32_to_bf16_rn(src[idx[k]]);
    ((unsigned short*)&o)[u] = v;
  }
  *(ushort4*)(w2c + (long long)n * 4096 + k4) = o;
}

// ================= 256x256 8-phase GEMM, reads pipelined 1 phase ahead =====
#define BUF_STRIDE 65536
#define BREG_OFF 32768
#define HALF_STRIDE 16384
#define WAVE_STRIDE 2048
#define INST_STRIDE 1024

#define STAGE_A(c, h, i, k0)                                                   \
  __builtin_amdgcn_global_load_lds(                                            \
      (const __attribute__((address_space(1))) void*)(Asrc +                   \
          ((h) * 128 + (i) * 8) * ldA + (k0)),                                 \
      (__attribute__((address_space(3))) void*)(&smem[(c) * BUF_STRIDE +       \
          (h) * HALF_STRIDE + w * WAVE_STRIDE + (i) * INST_STRIDE]),           \
      16, 0, 0)

#define STAGE_B(c, h, i, k0)                                                   \
  __builtin_amdgcn_global_load_lds(                                            \
      (const __attribute__((address_space(1))) void*)(Bsrc +                   \
          ((h) * 128 + (i) * 8) * ldB + (k0)),                                 \
      (__attribute__((address_space(3))) void*)(&smem[(c) * BUF_STRIDE +       \
          BREG_OFF + (h) * HALF_STRIDE + w * WAVE_STRIDE + (i) * INST_STRIDE]),\
      16, 0, 0)

template <int EPI>
__global__ __launch_bounds__(512, 2) void gemm256_kernel(
    const bf16_t* __restrict__ A, const bf16_t* __restrict__ B,
    void* __restrict__ Cout, long long ldA, long long ldB, long long ldC,
    int Kfix, const int* __restrict__ meta) {
  const int kpad = meta[1];
  const int nwg = gridDim.x * gridDim.y;
  const int bid = blockIdx.y * gridDim.x + blockIdx.x;
  const int swz = (bid & 7) * (nwg >> 3) + (bid >> 3);
  const int bx = swz % gridDim.x;
  const int by = swz / gridDim.x;
  const long long brow = (long long)by * 256;
  const long long bcol = (long long)bx * 256;
  if (EPI == 1 && bcol >= kpad) return;
  const int K = (EPI == 0) ? kpad : Kfix;
  const int NT = K >> 6;

  __shared__ __align__(16) char smem[131072];

  const int tid = threadIdx.x;
  const int l = tid & 63;
  const int w = tid >> 6;
  const int wm = w >> 2;
  const int wn = w & 3;

  const int srow = w * 16 + (l >> 3);
  const int sgran = (l & 7) ^ (l >> 3);
  const bf16_t* Asrc = A + (brow + srow) * ldA + sgran * 8;
  const bf16_t* Bsrc = B + (bcol + srow) * ldB + sgran * 8;

  const int g0 = (l >> 4) ^ (l & 7);
  const int aoff = (wm * 128 + (l & 15)) * 128 + g0 * 16;
  const int boff = BREG_OFF + (wn * 64 + (l & 15)) * 128 + g0 * 16;

  f32x4 acc[8][4];
#pragma unroll
  for (int m = 0; m < 8; ++m)
#pragma unroll
    for (int n = 0; n < 4; ++n) acc[m][n] = (f32x4){0.f, 0.f, 0.f, 0.f};

  bf16x8 a_lo[4][2], a_hi[4][2], b[4][2];

  // ---- prologue: tile0 full, tile1 A-halves ----
  STAGE_A(0, 0, 0, 0); STAGE_A(0, 0, 1, 0); STAGE_A(0, 1, 0, 0); STAGE_A(0, 1, 1, 0);
  STAGE_B(0, 0, 0, 0); STAGE_B(0, 0, 1, 0); STAGE_B(0, 1, 0, 0); STAGE_B(0, 1, 1, 0);
  STAGE_A(1, 0, 0, 64); STAGE_A(1, 0, 1, 64); STAGE_A(1, 1, 0, 64); STAGE_A(1, 1, 1, 64);
  asm volatile("s_waitcnt vmcnt(4)" ::: "memory");
  __builtin_amdgcn_s_barrier();

  for (int t = 0; t < NT; ++t) {
    const int c = t & 1;
    const int cb = c * BUF_STRIDE;
    const int k1 = (t + 1) << 6;
    const int k2 = (t + 2) << 6;

    // ---- tile-start reads: a_lo (m0-3), b01 ----
#pragma unroll
    for (int m = 0; m < 4; ++m)
#pragma unroll
      for (int kk = 0; kk < 2; ++kk)
        a_lo[m][kk] =
            *(const bf16x8*)&smem[cb + ((aoff + m * 2048) ^ (kk * 64))];
#pragma unroll
    for (int n = 0; n < 2; ++n)
#pragma unroll
      for (int kk = 0; kk < 2; ++kk)
        b[n][kk] = *(const bf16x8*)&smem[cb + ((boff + n * 2048) ^ (kk * 64))];

    // ===== p0: stage B-half0(t+1); read b23; MFMA q0 = a_lo x b01 =====
    if (t + 1 < NT) { STAGE_B(c ^ 1, 0, 0, k1); STAGE_B(c ^ 1, 0, 1, k1); }
#pragma unroll
    for (int n = 2; n < 4; ++n)
#pragma unroll
      for (int kk = 0; kk < 2; ++kk)
        b[n][kk] = *(const bf16x8*)&smem[cb + ((boff + n * 2048) ^ (kk * 64))];
    __builtin_amdgcn_s_barrier();
    __builtin_amdgcn_s_setprio(1);
#pragma unroll
    for (int m = 0; m < 4; ++m)
#pragma unroll
      for (int n = 0; n < 2; ++n)
#pragma unroll
        for (int kk = 0; kk < 2; ++kk)
          acc[m][n] = __builtin_amdgcn_mfma_f32_16x16x32_bf16(
              a_lo[m][kk], b[n][kk], acc[m][n], 0, 0, 0);
    __builtin_amdgcn_s_setprio(0);
    __builtin_amdgcn_s_barrier();

    // ===== p1: stage B-half1(t+1); read a_hi; MFMA q1 = a_lo x b23 =====
    if (t + 1 < NT) { STAGE_B(c ^ 1, 1, 0, k1); STAGE_B(c ^ 1, 1, 1, k1); }
#pragma unroll
    for (int m = 0; m < 4; ++m)
#pragma unroll
      for (int kk = 0; kk < 2; ++kk)
        a_hi[m][kk] =
            *(const bf16x8*)&smem[cb + ((aoff + (m + 4) * 2048) ^ (kk * 64))];
    __builtin_amdgcn_s_barrier();
    __builtin_amdgcn_s_setprio(1);
#pragma unroll
    for (int m = 0; m < 4; ++m)
#pragma unroll
      for (int n = 2; n < 4; ++n)
#pragma unroll
        for (int kk = 0; kk < 2; ++kk)
          acc[m][n] = __builtin_amdgcn_mfma_f32_16x16x32_bf16(
              a_lo[m][kk], b[n][kk], acc[m][n], 0, 0, 0);
    __builtin_amdgcn_s_setprio(0);
    __builtin_amdgcn_s_barrier();

    // ===== p2: MFMA q2 = a_hi x b01 =====
    __builtin_amdgcn_s_setprio(1);
#pragma unroll
    for (int m = 0; m < 4; ++m)
#pragma unroll
      for (int n = 0; n < 2; ++n)
#pragma unroll
        for (int kk = 0; kk < 2; ++kk)
          acc[m + 4][n] = __builtin_amdgcn_mfma_f32_16x16x32_bf16(
              a_hi[m][kk], b[n][kk], acc[m + 4][n], 0, 0, 0);
    __builtin_amdgcn_s_setprio(0);
    __builtin_amdgcn_s_barrier();

    // ===== p3: stage A(t+2); counted vmcnt; MFMA q3 = a_hi x b23 =====
    if (t + 2 < NT) {
      STAGE_A(c, 0, 0, k2); STAGE_A(c, 0, 1, k2);
      STAGE_A(c, 1, 0, k2); STAGE_A(c, 1, 1, k2);
      asm volatile("s_waitcnt vmcnt(4)" ::: "memory");
    } else if (t + 1 < NT) {
      asm volatile("s_waitcnt vmcnt(0)" ::: "memory");
    }
    __builtin_amdgcn_s_barrier();
    __builtin_amdgcn_s_setprio(1);
#pragma unroll
    for (int m = 0; m < 4; ++m)
#pragma unroll
      for (int n = 2; n < 4; ++n)
#pragma unroll
        for (int kk = 0; kk < 2; ++kk)
          acc[m + 4][n] = __builtin_amdgcn_mfma_f32_16x16x32_bf16(
              a_hi[m][kk], b[n][kk], acc[m + 4][n], 0, 0, 0);
    __builtin_amdgcn_s_setprio(0);
    __builtin_amdgcn_s_barrier();
  }

  // ---- epilogue ----
  const int orow = wm * 128 + ((l >> 4) << 2);
  const int ocol = wn * 64 + (l & 15);
#pragma unroll
  for (int m = 0; m < 8; ++m)
#pragma unroll
    for (int n = 0; n < 4; ++n)
#pragma unroll
      for (int r = 0; r < 4; ++r) {
        long long row = brow + orow + m * 16 + r;
        long long col = bcol + ocol + n * 16;
        float v = acc[m][n][r];
        if (EPI == 1) {
          ((unsigned short*)Cout)[row * ldC + col] =
              f32_to_bf16_rn(gelu_exact(v));
        } else {
          ((float*)Cout)[row * ldC + col] = v;
        }
      }
}

extern "C" void kernel_launch(void* const* d_in, const int* in_sizes, int n_in,
                              void* d_out, int out_size, void* d_ws,
                              size_t ws_size, hipStream_t stream) {
  const float* x = (const float*)d_in[0];
  const float* w1 = (const float*)d_in[1];
  const float* w2 = (const float*)d_in[2];
  const float* mask1 = (const float*)d_in[3];
  const float* mask2 = (const float*)d_in[4];
  float* out = (float*)d_out;

  const int D = 2048, H = 8192, M = 8192;
  const int KP = 4096;

  char* ws = (char*)d_ws;
  unsigned short* xb = (unsigned short*)ws;
  unsigned short* w1c = xb + (size_t)M * D;
  unsigned short* w2c = w1c + (size_t)KP * D;
  unsigned short* hb = w2c + (size_t)D * KP;
  int* idx = (int*)(hb + (size_t)M * KP);
  int* meta = idx + KP;

  build_idx_kernel<<<1, 1024, 0, stream>>>(mask1, mask2, idx, meta, H, D);

  {
    int n4 = (M * D) / 4;
    cast_x_kernel<<<n4 / 256, 256, 0, stream>>>(x, xb, n4);
  }
  {
    int nq = KP * (D / 4);
    compact_w1_kernel<<<nq / 256, 256, 0, stream>>>(w1, idx, meta, w1c, D);
  }
  {
    int nq = D * (KP / 4);
    compact_w2_kernel<<<nq / 256, 256, 0, stream>>>(w2, idx, meta, w2c, H);
  }

  // h[:, 0:kpad] = gelu(x @ w1c^T): M=8192, N<=4096 (early-exit), K=2048
  {
    dim3 grid(KP / 256, M / 256);
    gemm256_kernel<1><<<grid, 512, 0, stream>>>(
        (const bf16_t*)xb, (const bf16_t*)w1c, hb, (long long)D, (long long)D,
        (long long)KP, D, meta);
  }
  // out = h @ w2c^T: M=8192, N=2048, K=kpad (dynamic)
  {
    dim3 grid(D / 256, M / 256);
    gemm256_kernel<0><<<grid, 512, 0, stream>>>(
        (const bf16_t*)hb, (const bf16_t*)w2c, out, (long long)KP,
        (long long)KP, (long long)D, 0, meta);
  }
}

// Round 5
// 270.969 us; speedup vs baseline: 1.0837x; 1.0837x over previous
//
#include <hip/hip_runtime.h>
#include <hip/hip_bf16.h>

typedef __bf16 bf16_t;
typedef __bf16 bf16x8 __attribute__((ext_vector_type(8)));
typedef float f32x4 __attribute__((ext_vector_type(4)));

__device__ __forceinline__ unsigned short f32_to_bf16_rn(float f) {
  unsigned u = __float_as_uint(f);
  u += 0x7fffu + ((u >> 16) & 1u);
  return (unsigned short)(u >> 16);
}

__device__ __forceinline__ float gelu_exact(float x) {
  return 0.5f * x * (1.0f + erff(x * 0.7071067811865475f));
}

// ---------------- cast x -> bf16 ----------------
__global__ void cast_x_kernel(const float* __restrict__ in,
                              unsigned short* __restrict__ out, int n4) {
  int i = blockIdx.x * blockDim.x + threadIdx.x;
  if (i >= n4) return;
  float4 v = ((const float4*)in)[i];
  ushort4 o;
  o.x = f32_to_bf16_rn(v.x);
  o.y = f32_to_bf16_rn(v.y);
  o.z = f32_to_bf16_rn(v.z);
  o.w = f32_to_bf16_rn(v.w);
  ((ushort4*)out)[i] = o;
}

// ---------------- build compacted index list (deterministic scan) ----------
__global__ void build_idx_kernel(const float* __restrict__ mask1,
                                 const float* __restrict__ mask2,
                                 int* __restrict__ idx, int* __restrict__ meta,
                                 int H, int D) {
  __shared__ int sums[1024];
  const int t = threadIdx.x;
  int flags[8];
  int tot = 0;
#pragma unroll
  for (int u = 0; u < 8; ++u) {
    int j = t * 8 + u;
    int f = (mask1[(long long)j * D] != 0.0f) && (mask2[j] != 0.0f);
    flags[u] = f;
    tot += f;
  }
  sums[t] = tot;
  __syncthreads();
  for (int off = 1; off < 1024; off <<= 1) {
    int v = (t >= off) ? sums[t - off] : 0;
    __syncthreads();
    sums[t] += v;
    __syncthreads();
  }
  int pos = sums[t] - tot;
#pragma unroll
  for (int u = 0; u < 8; ++u) {
    if (flags[u]) idx[pos++] = t * 8 + u;
  }
  if (t == 1023) {
    int count = sums[1023];
    meta[0] = count;
    meta[1] = (count + 127) & ~127;
  }
}

// ---------------- compact + cast w1 rows ----------------
__global__ void compact_w1_kernel(const float* __restrict__ w1,
                                  const int* __restrict__ idx,
                                  const int* __restrict__ meta,
                                  unsigned short* __restrict__ w1c, int D) {
  int q = blockIdx.x * blockDim.x + threadIdx.x;
  int k = q >> 9;
  int d4 = (q & 511) << 2;
  int count = meta[0];
  ushort4 o = {0, 0, 0, 0};
  if (k < count) {
    int j = idx[k];
    float4 v = *(const float4*)(w1 + (long long)j * D + d4);
    o.x = f32_to_bf16_rn(v.x);
    o.y = f32_to_bf16_rn(v.y);
    o.z = f32_to_bf16_rn(v.z);
    o.w = f32_to_bf16_rn(v.w);
  }
  *(ushort4*)(w1c + (long long)k * D + d4) = o;
}

// ---------------- compact + cast w2 cols (ld 4096) ----------------
__global__ void compact_w2_kernel(const float* __restrict__ w2,
                                  const int* __restrict__ idx,
                                  const int* __restrict__ meta,
                                  unsigned short* __restrict__ w2c, int H) {
  int q = blockIdx.x * blockDim.x + threadIdx.x;
  int n = q >> 10;
  int k4 = (q & 1023) << 2;
  int count = meta[0];
  ushort4 o = {0, 0, 0, 0};
  const float* src = w2 + (long long)n * H;
#pragma unroll
  for (int u = 0; u < 4; ++u) {
    int k = k4 + u;
    unsigned short v = 0;
    if (k < count) v = f32_to_bf16_rn(src[idx[k]]);
    ((unsigned short*)&o)[u] = v;
  }
  *(ushort4*)(w2c + (long long)n * 4096 + k4) = o;
}

// ================= 256x256 GEMM, minimal 2-phase schedule ==================
// C[M,N] = A[M,K]*B[N,K]^T. BM=BN=256, BK=64, 8 waves (2Mx4N).
// Per K-tile: STAGE(next tile, 8x gl_lds) -> 24x ds_read (cur) -> 64 MFMA
// -> ONE __syncthreads() (intended vmcnt(0)+lgkm drain).
// T2 XOR swizzle both-sides. EPI==1: gelu->bf16; EPI==0: fp32.
#define BUF_STRIDE 65536
#define BREG_OFF 32768
#define HALF_STRIDE 16384
#define WAVE_STRIDE 2048
#define INST_STRIDE 1024

#define STAGE_A(c, h, i, k0)                                                   \
  __builtin_amdgcn_global_load_lds(                                            \
      (const __attribute__((address_space(1))) void*)(Asrc +                   \
          ((h) * 128 + (i) * 8) * ldA + (k0)),                                 \
      (__attribute__((address_space(3))) void*)(&smem[(c) * BUF_STRIDE +       \
          (h) * HALF_STRIDE + w * WAVE_STRIDE + (i) * INST_STRIDE]),           \
      16, 0, 0)

#define STAGE_B(c, h, i, k0)                                                   \
  __builtin_amdgcn_global_load_lds(                                            \
      (const __attribute__((address_space(1))) void*)(Bsrc +                   \
          ((h) * 128 + (i) * 8) * ldB + (k0)),                                 \
      (__attribute__((address_space(3))) void*)(&smem[(c) * BUF_STRIDE +       \
          BREG_OFF + (h) * HALF_STRIDE + w * WAVE_STRIDE + (i) * INST_STRIDE]),\
      16, 0, 0)

#define STAGE_TILE(c, k0)                                                      \
  do {                                                                         \
    STAGE_A(c, 0, 0, k0); STAGE_A(c, 0, 1, k0);                                \
    STAGE_A(c, 1, 0, k0); STAGE_A(c, 1, 1, k0);                                \
    STAGE_B(c, 0, 0, k0); STAGE_B(c, 0, 1, k0);                                \
    STAGE_B(c, 1, 0, k0); STAGE_B(c, 1, 1, k0);                                \
  } while (0)

template <int EPI>
__global__ __launch_bounds__(512, 2) void gemm256_kernel(
    const bf16_t* __restrict__ A, const bf16_t* __restrict__ B,
    void* __restrict__ Cout, long long ldA, long long ldB, long long ldC,
    int Kfix, const int* __restrict__ meta) {
  const int kpad = meta[1];
  const int nwg = gridDim.x * gridDim.y;
  const int bid = blockIdx.y * gridDim.x + blockIdx.x;
  const int swz = (bid & 7) * (nwg >> 3) + (bid >> 3);
  const int bx = swz % gridDim.x;
  const int by = swz / gridDim.x;
  const long long brow = (long long)by * 256;
  const long long bcol = (long long)bx * 256;
  if (EPI == 1 && bcol >= kpad) return;
  const int K = (EPI == 0) ? kpad : Kfix;
  const int NT = K >> 6;

  __shared__ __align__(16) char smem[131072];

  const int tid = threadIdx.x;
  const int l = tid & 63;
  const int w = tid >> 6;
  const int wm = w >> 2;
  const int wn = w & 3;

  // staging: per-lane global src with inverse column swizzle, linear LDS dest
  const int srow = w * 16 + (l >> 3);
  const int sgran = (l & 7) ^ (l >> 3);
  const bf16_t* Asrc = A + (brow + srow) * ldA + sgran * 8;
  const bf16_t* Bsrc = B + (bcol + srow) * ldB + sgran * 8;

  // swizzled ds_read offsets
  const int g0 = (l >> 4) ^ (l & 7);
  const int aoff = (wm * 128 + (l & 15)) * 128 + g0 * 16;
  const int boff = BREG_OFF + (wn * 64 + (l & 15)) * 128 + g0 * 16;

  f32x4 acc[8][4];
#pragma unroll
  for (int m = 0; m < 8; ++m)
#pragma unroll
    for (int n = 0; n < 4; ++n) acc[m][n] = (f32x4){0.f, 0.f, 0.f, 0.f};

  bf16x8 a[8][2], b[4][2];

  // prologue: stage tile 0
  STAGE_TILE(0, 0);
  __syncthreads();

  for (int t = 0; t < NT; ++t) {
    const int c = t & 1;
    const int cb = c * BUF_STRIDE;
    // stage next tile into other buffer
    if (t + 1 < NT) {
      const int k1 = (t + 1) << 6;
      STAGE_TILE(c ^ 1, k1);
    }
    // read current tile fragments
#pragma unroll
    for (int m = 0; m < 8; ++m)
#pragma unroll
      for (int kk = 0; kk < 2; ++kk)
        a[m][kk] = *(const bf16x8*)&smem[cb + ((aoff + m * 2048) ^ (kk * 64))];
#pragma unroll
    for (int n = 0; n < 4; ++n)
#pragma unroll
      for (int kk = 0; kk < 2; ++kk)
        b[n][kk] = *(const bf16x8*)&smem[cb + ((boff + n * 2048) ^ (kk * 64))];
    // MFMA: kk-outer, 32 independent per kk
#pragma unroll
    for (int kk = 0; kk < 2; ++kk)
#pragma unroll
      for (int m = 0; m < 8; ++m)
#pragma unroll
        for (int n = 0; n < 4; ++n)
          acc[m][n] = __builtin_amdgcn_mfma_f32_16x16x32_bf16(
              a[m][kk], b[n][kk], acc[m][n], 0, 0, 0);
    __syncthreads();
  }

  // epilogue
  const int orow = wm * 128 + ((l >> 4) << 2);
  const int ocol = wn * 64 + (l & 15);
#pragma unroll
  for (int m = 0; m < 8; ++m)
#pragma unroll
    for (int n = 0; n < 4; ++n)
#pragma unroll
      for (int r = 0; r < 4; ++r) {
        long long row = brow + orow + m * 16 + r;
        long long col = bcol + ocol + n * 16;
        float v = acc[m][n][r];
        if (EPI == 1) {
          ((unsigned short*)Cout)[row * ldC + col] =
              f32_to_bf16_rn(gelu_exact(v));
        } else {
          ((float*)Cout)[row * ldC + col] = v;
        }
      }
}

extern "C" void kernel_launch(void* const* d_in, const int* in_sizes, int n_in,
                              void* d_out, int out_size, void* d_ws,
                              size_t ws_size, hipStream_t stream) {
  const float* x = (const float*)d_in[0];
  const float* w1 = (const float*)d_in[1];
  const float* w2 = (const float*)d_in[2];
  const float* mask1 = (const float*)d_in[3];
  const float* mask2 = (const float*)d_in[4];
  float* out = (float*)d_out;

  const int D = 2048, H = 8192, M = 8192;
  const int KP = 4096;

  char* ws = (char*)d_ws;
  unsigned short* xb = (unsigned short*)ws;
  unsigned short* w1c = xb + (size_t)M * D;
  unsigned short* w2c = w1c + (size_t)KP * D;
  unsigned short* hb = w2c + (size_t)D * KP;
  int* idx = (int*)(hb + (size_t)M * KP);
  int* meta = idx + KP;

  build_idx_kernel<<<1, 1024, 0, stream>>>(mask1, mask2, idx, meta, H, D);

  {
    int n4 = (M * D) / 4;
    cast_x_kernel<<<n4 / 256, 256, 0, stream>>>(x, xb, n4);
  }
  {
    int nq = KP * (D / 4);
    compact_w1_kernel<<<nq / 256, 256, 0, stream>>>(w1, idx, meta, w1c, D);
  }
  {
    int nq = D * (KP / 4);
    compact_w2_kernel<<<nq / 256, 256, 0, stream>>>(w2, idx, meta, w2c, H);
  }

  // h[:, 0:kpad] = gelu(x @ w1c^T): M=8192, N<=4096 (early-exit), K=2048
  {
    dim3 grid(KP / 256, M / 256);
    gemm256_kernel<1><<<grid, 512, 0, stream>>>(
        (const bf16_t*)xb, (const bf16_t*)w1c, hb, (long long)D, (long long)D,
        (long long)KP, D, meta);
  }
  // out = h @ w2c^T: M=8192, N=2048, K=kpad (dynamic)
  {
    dim3 grid(D / 256, M / 256);
    gemm256_kernel<0><<<grid, 512, 0, stream>>>(
        (const bf16_t*)hb, (const bf16_t*)w2c, out, (long long)KP,
        (long long)KP, (long long)D, 0, meta);
  }
}